// Round 1
// baseline (3088.420 us; speedup 1.0000x reference)
//
#include <hip/hip_runtime.h>
#include <hip/hip_bf16.h>

#define IN_CH 128
#define D1 256      // HEADS*HID
#define HID 64
#define HEADS 4

__device__ __forceinline__ float lrelu02(float v) { return v > 0.f ? v : 0.2f * v; }
__device__ __forceinline__ float lrelu001(float v) { return v > 0.f ? v : 0.01f * v; }

// ---------------- GEMM1: h1[N,256] = x[N,128] @ W1[128,256] ----------------
__global__ __launch_bounds__(256) void gemm1_kernel(const float* __restrict__ x,
                                                    const float* __restrict__ W,
                                                    float* __restrict__ h, int n) {
    __shared__ float xs[32][IN_CH];   // 16 KB
    const int t = threadIdx.x;
    const int col = t;                // 0..255
    const int row0 = blockIdx.x * 32;
    #pragma unroll
    for (int i = 0; i < 4; ++i) {
        int f = i * 1024 + t * 4;
        int r = f >> 7, k = f & 127;
        int gr = row0 + r;
        float4 v = make_float4(0.f, 0.f, 0.f, 0.f);
        if (gr < n) v = *(const float4*)&x[gr * IN_CH + k];
        *(float4*)&xs[r][k] = v;
    }
    __syncthreads();
    float acc[32];
    #pragma unroll
    for (int r = 0; r < 32; ++r) acc[r] = 0.f;
    for (int k = 0; k < IN_CH; k += 4) {
        float w0 = W[(k + 0) * D1 + col];
        float w1 = W[(k + 1) * D1 + col];
        float w2 = W[(k + 2) * D1 + col];
        float w3 = W[(k + 3) * D1 + col];
        #pragma unroll
        for (int r = 0; r < 32; ++r) {
            float4 xv = *(const float4*)&xs[r][k];
            acc[r] = fmaf(xv.x, w0, acc[r]);
            acc[r] = fmaf(xv.y, w1, acc[r]);
            acc[r] = fmaf(xv.z, w2, acc[r]);
            acc[r] = fmaf(xv.w, w3, acc[r]);
        }
    }
    #pragma unroll
    for (int r = 0; r < 32; ++r) {
        int gr = row0 + r;
        if (gr < n) h[gr * D1 + col] = acc[r];
    }
}

// ---------------- GEMM2: h2[N,64] = hmid[N,256] @ W2[256,64] ----------------
__global__ __launch_bounds__(256) void gemm2_kernel(const float* __restrict__ x,
                                                    const float* __restrict__ W,
                                                    float* __restrict__ h, int n) {
    __shared__ float xs[32][D1];   // 32 KB
    const int t = threadIdx.x;
    const int col = t & 63;
    const int rseg = t >> 6;       // 0..3
    const int row0 = blockIdx.x * 32;
    #pragma unroll
    for (int i = 0; i < 8; ++i) {
        int f = i * 1024 + t * 4;
        int r = f >> 8, k = f & 255;
        int gr = row0 + r;
        float4 v = make_float4(0.f, 0.f, 0.f, 0.f);
        if (gr < n) v = *(const float4*)&x[gr * D1 + k];
        *(float4*)&xs[r][k] = v;
    }
    __syncthreads();
    float acc[8];
    #pragma unroll
    for (int r = 0; r < 8; ++r) acc[r] = 0.f;
    const int rbase = rseg * 8;
    for (int k = 0; k < D1; k += 4) {
        float w0 = W[(k + 0) * HID + col];
        float w1 = W[(k + 1) * HID + col];
        float w2 = W[(k + 2) * HID + col];
        float w3 = W[(k + 3) * HID + col];
        #pragma unroll
        for (int r = 0; r < 8; ++r) {
            float4 xv = *(const float4*)&xs[rbase + r][k];
            acc[r] = fmaf(xv.x, w0, acc[r]);
            acc[r] = fmaf(xv.y, w1, acc[r]);
            acc[r] = fmaf(xv.z, w2, acc[r]);
            acc[r] = fmaf(xv.w, w3, acc[r]);
        }
    }
    #pragma unroll
    for (int r = 0; r < 8; ++r) {
        int gr = row0 + rbase + r;
        if (gr < n) h[gr * HID + col] = acc[r];
    }
}

// ---- init1: per node compute alpha_src/alpha_dst (4 heads) and self-loop init ----
__global__ __launch_bounds__(256) void init1_kernel(const float* __restrict__ h1,
                                                    const float* __restrict__ a_src,
                                                    const float* __restrict__ a_dst,
                                                    float* __restrict__ as1, float* __restrict__ ad1,
                                                    float* __restrict__ accum, float* __restrict__ denom,
                                                    int n) {
    const int lane = threadIdx.x & 63;
    const int node = (blockIdx.x * 256 + threadIdx.x) >> 6;
    if (node >= n) return;
    const int hh = lane >> 4;            // head 0..3
    const int c0 = (lane & 15) * 4;      // channel-within-head base
    float4 hv = *(const float4*)&h1[node * D1 + lane * 4];
    float4 av = *(const float4*)&a_src[hh * HID + c0];
    float4 bv = *(const float4*)&a_dst[hh * HID + c0];
    float ps = hv.x * av.x + hv.y * av.y + hv.z * av.z + hv.w * av.w;
    float pd = hv.x * bv.x + hv.y * bv.y + hv.z * bv.z + hv.w * bv.w;
    #pragma unroll
    for (int off = 1; off < 16; off <<= 1) {
        ps += __shfl_xor(ps, off, 64);
        pd += __shfl_xor(pd, off, 64);
    }
    float w = expf(lrelu02(ps + pd));    // self-loop weight (src==dst)
    *(float4*)&accum[node * D1 + lane * 4] =
        make_float4(hv.x * w, hv.y * w, hv.z * w, hv.w * w);
    if ((lane & 15) == 0) {
        as1[node * 4 + hh] = ps;
        ad1[node * 4 + hh] = pd;
        denom[node * 4 + hh] = w;
    }
}

// ---- edge1: one wave per edge; scatter weighted messages (4 heads x 64 ch) ----
__global__ __launch_bounds__(256) void edge1_kernel(const int* __restrict__ ei,
                                                    const float* __restrict__ h1,
                                                    const float* __restrict__ as1,
                                                    const float* __restrict__ ad1,
                                                    float* __restrict__ accum,
                                                    float* __restrict__ denom, int nE) {
    const int lane = threadIdx.x & 63;
    const int e = (blockIdx.x * 256 + threadIdx.x) >> 6;
    if (e >= nE) return;
    const int src = ei[e];
    const int dst = ei[nE + e];
    const int hh = lane >> 4;
    float logit = as1[src * 4 + hh] + ad1[dst * 4 + hh];
    float w = expf(lrelu02(logit));
    float4 hv = *(const float4*)&h1[src * D1 + lane * 4];
    float* ap = &accum[dst * D1 + lane * 4];
    atomicAdd(ap + 0, hv.x * w);
    atomicAdd(ap + 1, hv.y * w);
    atomicAdd(ap + 2, hv.z * w);
    atomicAdd(ap + 3, hv.w * w);
    if ((lane & 15) == 0) atomicAdd(&denom[dst * 4 + hh], w);
}

// ---- post1: y = accum/denom + b1 -> LayerNorm -> LeakyReLU(0.01) -> hmid ----
__global__ __launch_bounds__(256) void post1_kernel(const float* __restrict__ accum,
                                                    const float* __restrict__ denom,
                                                    const float* __restrict__ b1,
                                                    const float* __restrict__ gamma,
                                                    const float* __restrict__ beta,
                                                    float* __restrict__ hmid, int n) {
    const int lane = threadIdx.x & 63;
    const int node = (blockIdx.x * 256 + threadIdx.x) >> 6;
    if (node >= n) return;
    const int hh = lane >> 4;
    float4 a = *(const float4*)&accum[node * D1 + lane * 4];
    float d = denom[node * 4 + hh] + 1e-16f;
    float4 bv = *(const float4*)&b1[lane * 4];
    float4 y;
    y.x = a.x / d + bv.x; y.y = a.y / d + bv.y;
    y.z = a.z / d + bv.z; y.w = a.w / d + bv.w;
    float s = y.x + y.y + y.z + y.w;
    #pragma unroll
    for (int off = 1; off < 64; off <<= 1) s += __shfl_xor(s, off, 64);
    float mu = s * (1.f / 256.f);
    float4 dx;
    dx.x = y.x - mu; dx.y = y.y - mu; dx.z = y.z - mu; dx.w = y.w - mu;
    float sq = dx.x * dx.x + dx.y * dx.y + dx.z * dx.z + dx.w * dx.w;
    #pragma unroll
    for (int off = 1; off < 64; off <<= 1) sq += __shfl_xor(sq, off, 64);
    float rs = rsqrtf(sq * (1.f / 256.f) + 1e-5f);
    float4 g = *(const float4*)&gamma[lane * 4];
    float4 be = *(const float4*)&beta[lane * 4];
    float4 o;
    o.x = lrelu001(dx.x * rs * g.x + be.x);
    o.y = lrelu001(dx.y * rs * g.y + be.y);
    o.z = lrelu001(dx.z * rs * g.z + be.z);
    o.w = lrelu001(dx.w * rs * g.w + be.w);
    *(float4*)&hmid[node * D1 + lane * 4] = o;
}

// ---- init2: per node alpha2 + self-loop init (1 head, 64 ch) ----
__global__ __launch_bounds__(256) void init2_kernel(const float* __restrict__ h2,
                                                    const float* __restrict__ a_src,
                                                    const float* __restrict__ a_dst,
                                                    float* __restrict__ as2, float* __restrict__ ad2,
                                                    float* __restrict__ accum, float* __restrict__ denom,
                                                    int n) {
    const int lane = threadIdx.x & 63;
    const int node = (blockIdx.x * 256 + threadIdx.x) >> 6;
    if (node >= n) return;
    float v = h2[node * HID + lane];
    float ps = v * a_src[lane];
    float pd = v * a_dst[lane];
    #pragma unroll
    for (int off = 1; off < 64; off <<= 1) {
        ps += __shfl_xor(ps, off, 64);
        pd += __shfl_xor(pd, off, 64);
    }
    float w = expf(lrelu02(ps + pd));
    accum[node * HID + lane] = v * w;
    if (lane == 0) {
        as2[node] = ps;
        ad2[node] = pd;
        denom[node] = w;
    }
}

// ---- edge2: one wave per edge (1 head x 64 ch) ----
__global__ __launch_bounds__(256) void edge2_kernel(const int* __restrict__ ei,
                                                    const float* __restrict__ h2,
                                                    const float* __restrict__ as2,
                                                    const float* __restrict__ ad2,
                                                    float* __restrict__ accum,
                                                    float* __restrict__ denom, int nE) {
    const int lane = threadIdx.x & 63;
    const int e = (blockIdx.x * 256 + threadIdx.x) >> 6;
    if (e >= nE) return;
    const int src = ei[e];
    const int dst = ei[nE + e];
    float w = expf(lrelu02(as2[src] + ad2[dst]));
    float v = h2[src * HID + lane];
    atomicAdd(&accum[dst * HID + lane], v * w);
    if (lane == 0) atomicAdd(&denom[dst], w);
}

// ---- post2: out = accum2/denom2 + b2 ----
__global__ __launch_bounds__(256) void post2_kernel(const float* __restrict__ accum,
                                                    const float* __restrict__ denom,
                                                    const float* __restrict__ b2,
                                                    float* __restrict__ out, int n) {
    int i = blockIdx.x * 256 + threadIdx.x;
    if (i >= n * HID) return;
    int node = i >> 6, c = i & 63;
    out[i] = accum[i] / (denom[node] + 1e-16f) + b2[c];
}

extern "C" void kernel_launch(void* const* d_in, const int* in_sizes, int n_in,
                              void* d_out, int out_size, void* d_ws, size_t ws_size,
                              hipStream_t stream) {
    const float* x      = (const float*)d_in[0];
    const int*   ei     = (const int*)d_in[1];
    const float* W1     = (const float*)d_in[2];
    const float* a_src1 = (const float*)d_in[3];
    const float* a_dst1 = (const float*)d_in[4];
    const float* b1     = (const float*)d_in[5];
    const float* gamma  = (const float*)d_in[6];
    const float* beta   = (const float*)d_in[7];
    const float* W2     = (const float*)d_in[8];
    const float* a_src2 = (const float*)d_in[9];
    const float* a_dst2 = (const float*)d_in[10];
    const float* b2     = (const float*)d_in[11];
    float* out = (float*)d_out;

    const int N = in_sizes[0] / IN_CH;
    const int E = in_sizes[1] / 2;

    // workspace layout (floats):
    //  bufA: N*256  (h1, later hmid)
    //  bufB: N*256  (accum1, later h2[0..N*64) + accum2[N*64..N*128))
    //  C:    as1,ad1,denom1 (N*4 each), as2,ad2,denom2 (N each)
    float* ws   = (float*)d_ws;
    float* bufA = ws;
    float* bufB = ws + (size_t)N * D1;
    float* C    = ws + (size_t)2 * N * D1;
    float* as1    = C;
    float* ad1    = C + (size_t)N * 4;
    float* denom1 = C + (size_t)N * 8;
    float* as2    = C + (size_t)N * 12;
    float* ad2    = as2 + N;
    float* denom2 = ad2 + N;
    float* h2     = bufB;
    float* accum2 = bufB + (size_t)N * HID;

    const int nodeBlocks = (N + 3) / 4;     // 4 waves (nodes) per 256-thread block
    const int edgeBlocks = (E + 3) / 4;

    gemm1_kernel<<<(N + 31) / 32, 256, 0, stream>>>(x, W1, bufA, N);
    init1_kernel<<<nodeBlocks, 256, 0, stream>>>(bufA, a_src1, a_dst1, as1, ad1, bufB, denom1, N);
    edge1_kernel<<<edgeBlocks, 256, 0, stream>>>(ei, bufA, as1, ad1, bufB, denom1, E);
    post1_kernel<<<nodeBlocks, 256, 0, stream>>>(bufB, denom1, b1, gamma, beta, bufA, N);
    gemm2_kernel<<<(N + 31) / 32, 256, 0, stream>>>(bufA, W2, h2, N);
    init2_kernel<<<nodeBlocks, 256, 0, stream>>>(h2, a_src2, a_dst2, as2, ad2, accum2, denom2, N);
    edge2_kernel<<<edgeBlocks, 256, 0, stream>>>(ei, h2, as2, ad2, accum2, denom2, E);
    post2_kernel<<<(N * HID + 255) / 256, 256, 0, stream>>>(accum2, denom2, b2, out, N);
}

// Round 2
// 435.960 us; speedup vs baseline: 7.0842x; 7.0842x over previous
//
#include <hip/hip_runtime.h>
#include <hip/hip_bf16.h>

#define IN_CH 128
#define D1 256      // HEADS*HID
#define HID 64
#define HEADS 4
#define SCAN_BLK 1024   // elements per scan block (256 threads x 4)

__device__ __forceinline__ float lrelu02(float v) { return v > 0.f ? v : 0.2f * v; }
__device__ __forceinline__ float lrelu001(float v) { return v > 0.f ? v : 0.01f * v; }

// ---------------- GEMM1: h1[N,256] = x[N,128] @ W1[128,256] ----------------
__global__ __launch_bounds__(256) void gemm1_kernel(const float* __restrict__ x,
                                                    const float* __restrict__ W,
                                                    float* __restrict__ h, int n) {
    __shared__ float xs[32][IN_CH];   // 16 KB
    const int t = threadIdx.x;
    const int col = t;                // 0..255
    const int row0 = blockIdx.x * 32;
    #pragma unroll
    for (int i = 0; i < 4; ++i) {
        int f = i * 1024 + t * 4;
        int r = f >> 7, k = f & 127;
        int gr = row0 + r;
        float4 v = make_float4(0.f, 0.f, 0.f, 0.f);
        if (gr < n) v = *(const float4*)&x[gr * IN_CH + k];
        *(float4*)&xs[r][k] = v;
    }
    __syncthreads();
    float acc[32];
    #pragma unroll
    for (int r = 0; r < 32; ++r) acc[r] = 0.f;
    for (int k = 0; k < IN_CH; k += 4) {
        float w0 = W[(k + 0) * D1 + col];
        float w1 = W[(k + 1) * D1 + col];
        float w2 = W[(k + 2) * D1 + col];
        float w3 = W[(k + 3) * D1 + col];
        #pragma unroll
        for (int r = 0; r < 32; ++r) {
            float4 xv = *(const float4*)&xs[r][k];
            acc[r] = fmaf(xv.x, w0, acc[r]);
            acc[r] = fmaf(xv.y, w1, acc[r]);
            acc[r] = fmaf(xv.z, w2, acc[r]);
            acc[r] = fmaf(xv.w, w3, acc[r]);
        }
    }
    #pragma unroll
    for (int r = 0; r < 32; ++r) {
        int gr = row0 + r;
        if (gr < n) h[gr * D1 + col] = acc[r];
    }
}

// ---------------- GEMM2: h2[N,64] = hmid[N,256] @ W2[256,64] ----------------
__global__ __launch_bounds__(256) void gemm2_kernel(const float* __restrict__ x,
                                                    const float* __restrict__ W,
                                                    float* __restrict__ h, int n) {
    __shared__ float xs[32][D1];   // 32 KB
    const int t = threadIdx.x;
    const int col = t & 63;
    const int rseg = t >> 6;       // 0..3
    const int row0 = blockIdx.x * 32;
    #pragma unroll
    for (int i = 0; i < 8; ++i) {
        int f = i * 1024 + t * 4;
        int r = f >> 8, k = f & 255;
        int gr = row0 + r;
        float4 v = make_float4(0.f, 0.f, 0.f, 0.f);
        if (gr < n) v = *(const float4*)&x[gr * D1 + k];
        *(float4*)&xs[r][k] = v;
    }
    __syncthreads();
    float acc[8];
    #pragma unroll
    for (int r = 0; r < 8; ++r) acc[r] = 0.f;
    const int rbase = rseg * 8;
    for (int k = 0; k < D1; k += 4) {
        float w0 = W[(k + 0) * HID + col];
        float w1 = W[(k + 1) * HID + col];
        float w2 = W[(k + 2) * HID + col];
        float w3 = W[(k + 3) * HID + col];
        #pragma unroll
        for (int r = 0; r < 8; ++r) {
            float4 xv = *(const float4*)&xs[rbase + r][k];
            acc[r] = fmaf(xv.x, w0, acc[r]);
            acc[r] = fmaf(xv.y, w1, acc[r]);
            acc[r] = fmaf(xv.z, w2, acc[r]);
            acc[r] = fmaf(xv.w, w3, acc[r]);
        }
    }
    #pragma unroll
    for (int r = 0; r < 8; ++r) {
        int gr = row0 + rbase + r;
        if (gr < n) h[gr * HID + col] = acc[r];
    }
}

// ================= CSR build (by destination) =================
__global__ __launch_bounds__(256) void zero_kernel(int* __restrict__ cnt, int n) {
    int i = blockIdx.x * 256 + threadIdx.x;
    if (i < n) cnt[i] = 0;
}

__global__ __launch_bounds__(256) void hist_kernel(const int* __restrict__ ei,
                                                   int* __restrict__ cnt, int nE) {
    int e = blockIdx.x * 256 + threadIdx.x;
    if (e >= nE) return;
    atomicAdd(&cnt[ei[nE + e]], 1);
}

// per-block exclusive scan (1024 elems / block), block totals out
__global__ __launch_bounds__(256) void scan1_kernel(const int* __restrict__ cnt,
                                                    int* __restrict__ pre,
                                                    int* __restrict__ blockSums, int n) {
    __shared__ int lds[256];
    const int t = threadIdx.x;
    const int base = blockIdx.x * SCAN_BLK + t * 4;
    int v0 = 0, v1 = 0, v2 = 0, v3 = 0;
    if (base + 0 < n) v0 = cnt[base + 0];
    if (base + 1 < n) v1 = cnt[base + 1];
    if (base + 2 < n) v2 = cnt[base + 2];
    if (base + 3 < n) v3 = cnt[base + 3];
    int s = v0 + v1 + v2 + v3;
    lds[t] = s;
    __syncthreads();
    for (int off = 1; off < 256; off <<= 1) {
        int x = 0;
        if (t >= off) x = lds[t - off];
        __syncthreads();
        if (t >= off) lds[t] += x;
        __syncthreads();
    }
    int excl = lds[t] - s;
    if (t == 255) blockSums[blockIdx.x] = lds[255];
    if (base + 0 < n) pre[base + 0] = excl;
    if (base + 1 < n) pre[base + 1] = excl + v0;
    if (base + 2 < n) pre[base + 2] = excl + v0 + v1;
    if (base + 3 < n) pre[base + 3] = excl + v0 + v1 + v2;
}

__global__ void scan2_kernel(int* __restrict__ blockSums, int nb) {
    if (threadIdx.x == 0 && blockIdx.x == 0) {
        int acc = 0;
        for (int i = 0; i < nb; ++i) { int v = blockSums[i]; blockSums[i] = acc; acc += v; }
    }
}

__global__ __launch_bounds__(256) void scan3_kernel(int* __restrict__ pre,
                                                    const int* __restrict__ blockSums,
                                                    int* __restrict__ cursor, int n, int nE) {
    int i = blockIdx.x * 256 + threadIdx.x;
    if (i < n) {
        int v = pre[i] + blockSums[i / SCAN_BLK];
        pre[i] = v;
        cursor[i] = v;
    }
    if (i == 0) pre[n] = nE;
}

__global__ __launch_bounds__(256) void scatter_kernel(const int* __restrict__ ei,
                                                      int* __restrict__ cursor,
                                                      int* __restrict__ srcIdx, int nE) {
    int e = blockIdx.x * 256 + threadIdx.x;
    if (e >= nE) return;
    int dst = ei[nE + e];
    int pos = atomicAdd(&cursor[dst], 1);
    srcIdx[pos] = ei[e];
}

// ---- alpha1: per node compute alpha_src/alpha_dst (4 heads) ----
__global__ __launch_bounds__(256) void alpha1_kernel(const float* __restrict__ h1,
                                                     const float* __restrict__ a_src,
                                                     const float* __restrict__ a_dst,
                                                     float* __restrict__ as1,
                                                     float* __restrict__ ad1, int n) {
    const int lane = threadIdx.x & 63;
    const int node = (blockIdx.x * 256 + threadIdx.x) >> 6;
    if (node >= n) return;
    const int hh = lane >> 4;
    const int c0 = (lane & 15) * 4;
    float4 hv = *(const float4*)&h1[node * D1 + lane * 4];
    float4 av = *(const float4*)&a_src[hh * HID + c0];
    float4 bv = *(const float4*)&a_dst[hh * HID + c0];
    float ps = hv.x * av.x + hv.y * av.y + hv.z * av.z + hv.w * av.w;
    float pd = hv.x * bv.x + hv.y * bv.y + hv.z * bv.z + hv.w * bv.w;
    #pragma unroll
    for (int off = 1; off < 16; off <<= 1) {
        ps += __shfl_xor(ps, off, 64);
        pd += __shfl_xor(pd, off, 64);
    }
    if ((lane & 15) == 0) {
        as1[node * 4 + hh] = ps;
        ad1[node * 4 + hh] = pd;
    }
}

// ---- gather1: wave per dst node; aggregate in-edges + self-loop; fused LN ----
__global__ __launch_bounds__(256) void gather1_kernel(const float* __restrict__ h1,
                                                      const float* __restrict__ as1,
                                                      const float* __restrict__ ad1,
                                                      const int* __restrict__ rowStart,
                                                      const int* __restrict__ srcIdx,
                                                      const float* __restrict__ b1,
                                                      const float* __restrict__ gamma,
                                                      const float* __restrict__ beta,
                                                      float* __restrict__ hmid, int n) {
    const int lane = threadIdx.x & 63;
    const int node = (blockIdx.x * 256 + threadIdx.x) >> 6;
    if (node >= n) return;
    const int hh = lane >> 4;
    const float ad_n = ad1[node * 4 + hh];
    const float as_n = as1[node * 4 + hh];
    float4 hv = *(const float4*)&h1[node * D1 + lane * 4];
    float w = expf(lrelu02(as_n + ad_n));           // self-loop
    float4 acc = make_float4(hv.x * w, hv.y * w, hv.z * w, hv.w * w);
    float den = w;
    const int beg = rowStart[node], end = rowStart[node + 1];
    int s_next = (beg < end) ? srcIdx[beg] : 0;
    for (int j = beg; j < end; ++j) {
        int s = s_next;
        if (j + 1 < end) s_next = srcIdx[j + 1];
        float wj = expf(lrelu02(as1[s * 4 + hh] + ad_n));
        float4 xv = *(const float4*)&h1[s * D1 + lane * 4];
        acc.x = fmaf(xv.x, wj, acc.x);
        acc.y = fmaf(xv.y, wj, acc.y);
        acc.z = fmaf(xv.z, wj, acc.z);
        acc.w = fmaf(xv.w, wj, acc.w);
        den += wj;
    }
    float inv = 1.f / (den + 1e-16f);
    float4 bv = *(const float4*)&b1[lane * 4];
    float4 y;
    y.x = acc.x * inv + bv.x; y.y = acc.y * inv + bv.y;
    y.z = acc.z * inv + bv.z; y.w = acc.w * inv + bv.w;
    // LayerNorm over 256 channels (64 lanes x 4)
    float s = y.x + y.y + y.z + y.w;
    #pragma unroll
    for (int off = 1; off < 64; off <<= 1) s += __shfl_xor(s, off, 64);
    float mu = s * (1.f / 256.f);
    float4 dx;
    dx.x = y.x - mu; dx.y = y.y - mu; dx.z = y.z - mu; dx.w = y.w - mu;
    float sq = dx.x * dx.x + dx.y * dx.y + dx.z * dx.z + dx.w * dx.w;
    #pragma unroll
    for (int off = 1; off < 64; off <<= 1) sq += __shfl_xor(sq, off, 64);
    float rs = rsqrtf(sq * (1.f / 256.f) + 1e-5f);
    float4 g = *(const float4*)&gamma[lane * 4];
    float4 be = *(const float4*)&beta[lane * 4];
    float4 o;
    o.x = lrelu001(dx.x * rs * g.x + be.x);
    o.y = lrelu001(dx.y * rs * g.y + be.y);
    o.z = lrelu001(dx.z * rs * g.z + be.z);
    o.w = lrelu001(dx.w * rs * g.w + be.w);
    *(float4*)&hmid[node * D1 + lane * 4] = o;
}

// ---- alpha2: per node alpha for layer 2 (1 head) ----
__global__ __launch_bounds__(256) void alpha2_kernel(const float* __restrict__ h2,
                                                     const float* __restrict__ a_src,
                                                     const float* __restrict__ a_dst,
                                                     float* __restrict__ as2,
                                                     float* __restrict__ ad2, int n) {
    const int lane = threadIdx.x & 63;
    const int node = (blockIdx.x * 256 + threadIdx.x) >> 6;
    if (node >= n) return;
    float v = h2[node * HID + lane];
    float ps = v * a_src[lane];
    float pd = v * a_dst[lane];
    #pragma unroll
    for (int off = 1; off < 64; off <<= 1) {
        ps += __shfl_xor(ps, off, 64);
        pd += __shfl_xor(pd, off, 64);
    }
    if (lane == 0) { as2[node] = ps; ad2[node] = pd; }
}

// ---- gather2: wave per dst node (1 head x 64 ch); fused bias ----
__global__ __launch_bounds__(256) void gather2_kernel(const float* __restrict__ h2,
                                                      const float* __restrict__ as2,
                                                      const float* __restrict__ ad2,
                                                      const int* __restrict__ rowStart,
                                                      const int* __restrict__ srcIdx,
                                                      const float* __restrict__ b2,
                                                      float* __restrict__ out, int n) {
    const int lane = threadIdx.x & 63;
    const int node = (blockIdx.x * 256 + threadIdx.x) >> 6;
    if (node >= n) return;
    const float ad_n = ad2[node];
    float v = h2[node * HID + lane];
    float w = expf(lrelu02(as2[node] + ad_n));      // self-loop
    float acc = v * w;
    float den = w;
    const int beg = rowStart[node], end = rowStart[node + 1];
    int s_next = (beg < end) ? srcIdx[beg] : 0;
    for (int j = beg; j < end; ++j) {
        int s = s_next;
        if (j + 1 < end) s_next = srcIdx[j + 1];
        float wj = expf(lrelu02(as2[s] + ad_n));
        acc = fmaf(h2[s * HID + lane], wj, acc);
        den += wj;
    }
    out[node * HID + lane] = acc / (den + 1e-16f) + b2[lane];
}

extern "C" void kernel_launch(void* const* d_in, const int* in_sizes, int n_in,
                              void* d_out, int out_size, void* d_ws, size_t ws_size,
                              hipStream_t stream) {
    const float* x      = (const float*)d_in[0];
    const int*   ei     = (const int*)d_in[1];
    const float* W1     = (const float*)d_in[2];
    const float* a_src1 = (const float*)d_in[3];
    const float* a_dst1 = (const float*)d_in[4];
    const float* b1     = (const float*)d_in[5];
    const float* gamma  = (const float*)d_in[6];
    const float* beta   = (const float*)d_in[7];
    const float* W2     = (const float*)d_in[8];
    const float* a_src2 = (const float*)d_in[9];
    const float* a_dst2 = (const float*)d_in[10];
    const float* b2     = (const float*)d_in[11];
    float* out = (float*)d_out;

    const int N = in_sizes[0] / IN_CH;
    const int E = in_sizes[1] / 2;

    // workspace layout
    float* ws   = (float*)d_ws;
    float* bufA = ws;                                  // N*256  h1, later h2 (N*64)
    float* bufB = bufA + (size_t)N * D1;               // N*256  hmid
    float* as1  = bufB + (size_t)N * D1;               // 4N
    float* ad1  = as1 + (size_t)N * 4;                 // 4N
    float* as2  = ad1 + (size_t)N * 4;                 // N
    float* ad2  = as2 + N;                             // N
    int* rowStart  = (int*)(ad2 + N);                  // N+1
    int* cursor    = rowStart + N + 1;                 // N
    int* srcIdx    = cursor + N;                       // E
    int* blockSums = srcIdx + E;                       // ~64

    float* h2 = bufA;   // reuse after h1 dead

    const int nodeBlocks = (N + 3) / 4;     // 4 waves (nodes) per 256-thread block
    const int nThreadBlocksN = (N + 255) / 256;
    const int nThreadBlocksE = (E + 255) / 256;
    const int scanBlocks = (N + SCAN_BLK - 1) / SCAN_BLK;

    // CSR build (by destination)
    zero_kernel<<<nThreadBlocksN, 256, 0, stream>>>(cursor, N);
    hist_kernel<<<nThreadBlocksE, 256, 0, stream>>>(ei, cursor, E);
    scan1_kernel<<<scanBlocks, 256, 0, stream>>>(cursor, rowStart, blockSums, N);
    scan2_kernel<<<1, 64, 0, stream>>>(blockSums, scanBlocks);
    scan3_kernel<<<nThreadBlocksN, 256, 0, stream>>>(rowStart, blockSums, cursor, N, E);
    scatter_kernel<<<nThreadBlocksE, 256, 0, stream>>>(ei, cursor, srcIdx, E);

    // layer 1
    gemm1_kernel<<<(N + 31) / 32, 256, 0, stream>>>(x, W1, bufA, N);
    alpha1_kernel<<<nodeBlocks, 256, 0, stream>>>(bufA, a_src1, a_dst1, as1, ad1, N);
    gather1_kernel<<<nodeBlocks, 256, 0, stream>>>(bufA, as1, ad1, rowStart, srcIdx,
                                                   b1, gamma, beta, bufB, N);
    // layer 2
    gemm2_kernel<<<(N + 31) / 32, 256, 0, stream>>>(bufB, W2, h2, N);
    alpha2_kernel<<<nodeBlocks, 256, 0, stream>>>(h2, a_src2, a_dst2, as2, ad2, N);
    gather2_kernel<<<nodeBlocks, 256, 0, stream>>>(h2, as2, ad2, rowStart, srcIdx,
                                                   b2, out, N);
}

// Round 3
// 359.985 us; speedup vs baseline: 8.5793x; 1.2110x over previous
//
#include <hip/hip_runtime.h>
#include <hip/hip_bf16.h>

#define IN_CH 128
#define D1 256      // HEADS*HID
#define HID 64
#define HEADS 4
#define SCAN_BLK 1024   // elements per scan block (256 threads x 4)

typedef _Float16 h16;
typedef __attribute__((ext_vector_type(4))) _Float16 half4v;

__device__ __forceinline__ float lrelu02(float v) { return v > 0.f ? v : 0.2f * v; }
__device__ __forceinline__ float lrelu001(float v) { return v > 0.f ? v : 0.01f * v; }

// ---------------- GEMM1: h1[N,256](fp16) = x[N,128] @ W1[128,256] ----------------
__global__ __launch_bounds__(256) void gemm1_kernel(const float* __restrict__ x,
                                                    const float* __restrict__ W,
                                                    h16* __restrict__ h, int n) {
    __shared__ float xs[32][IN_CH];   // 16 KB
    const int t = threadIdx.x;
    const int col = t;                // 0..255
    const int row0 = blockIdx.x * 32;
    #pragma unroll
    for (int i = 0; i < 4; ++i) {
        int f = i * 1024 + t * 4;
        int r = f >> 7, k = f & 127;
        int gr = row0 + r;
        float4 v = make_float4(0.f, 0.f, 0.f, 0.f);
        if (gr < n) v = *(const float4*)&x[gr * IN_CH + k];
        *(float4*)&xs[r][k] = v;
    }
    __syncthreads();
    float acc[32];
    #pragma unroll
    for (int r = 0; r < 32; ++r) acc[r] = 0.f;
    for (int k = 0; k < IN_CH; k += 4) {
        float w0 = W[(k + 0) * D1 + col];
        float w1 = W[(k + 1) * D1 + col];
        float w2 = W[(k + 2) * D1 + col];
        float w3 = W[(k + 3) * D1 + col];
        #pragma unroll
        for (int r = 0; r < 32; ++r) {
            float4 xv = *(const float4*)&xs[r][k];
            acc[r] = fmaf(xv.x, w0, acc[r]);
            acc[r] = fmaf(xv.y, w1, acc[r]);
            acc[r] = fmaf(xv.z, w2, acc[r]);
            acc[r] = fmaf(xv.w, w3, acc[r]);
        }
    }
    #pragma unroll
    for (int r = 0; r < 32; ++r) {
        int gr = row0 + r;
        if (gr < n) h[(size_t)gr * D1 + col] = (h16)acc[r];
    }
}

// ---------------- GEMM2: h2[N,64](fp16) = hmid[N,256] @ W2[256,64] ----------------
__global__ __launch_bounds__(256) void gemm2_kernel(const float* __restrict__ x,
                                                    const float* __restrict__ W,
                                                    h16* __restrict__ h, int n) {
    __shared__ float xs[32][D1];   // 32 KB
    const int t = threadIdx.x;
    const int col = t & 63;
    const int rseg = t >> 6;       // 0..3
    const int row0 = blockIdx.x * 32;
    #pragma unroll
    for (int i = 0; i < 8; ++i) {
        int f = i * 1024 + t * 4;
        int r = f >> 8, k = f & 255;
        int gr = row0 + r;
        float4 v = make_float4(0.f, 0.f, 0.f, 0.f);
        if (gr < n) v = *(const float4*)&x[gr * D1 + k];
        *(float4*)&xs[r][k] = v;
    }
    __syncthreads();
    float acc[8];
    #pragma unroll
    for (int r = 0; r < 8; ++r) acc[r] = 0.f;
    const int rbase = rseg * 8;
    for (int k = 0; k < D1; k += 4) {
        float w0 = W[(k + 0) * HID + col];
        float w1 = W[(k + 1) * HID + col];
        float w2 = W[(k + 2) * HID + col];
        float w3 = W[(k + 3) * HID + col];
        #pragma unroll
        for (int r = 0; r < 8; ++r) {
            float4 xv = *(const float4*)&xs[rbase + r][k];
            acc[r] = fmaf(xv.x, w0, acc[r]);
            acc[r] = fmaf(xv.y, w1, acc[r]);
            acc[r] = fmaf(xv.z, w2, acc[r]);
            acc[r] = fmaf(xv.w, w3, acc[r]);
        }
    }
    #pragma unroll
    for (int r = 0; r < 8; ++r) {
        int gr = row0 + rbase + r;
        if (gr < n) h[(size_t)gr * HID + col] = (h16)acc[r];
    }
}

// ================= CSR build (by destination) =================
__global__ __launch_bounds__(256) void zero_kernel(int* __restrict__ cnt, int n) {
    int i = blockIdx.x * 256 + threadIdx.x;
    if (i < n) cnt[i] = 0;
}

__global__ __launch_bounds__(256) void hist_kernel(const int* __restrict__ ei,
                                                   int* __restrict__ cnt, int nE) {
    int e = blockIdx.x * 256 + threadIdx.x;
    if (e >= nE) return;
    atomicAdd(&cnt[ei[nE + e]], 1);
}

__global__ __launch_bounds__(256) void scan1_kernel(const int* __restrict__ cnt,
                                                    int* __restrict__ pre,
                                                    int* __restrict__ blockSums, int n) {
    __shared__ int lds[256];
    const int t = threadIdx.x;
    const int base = blockIdx.x * SCAN_BLK + t * 4;
    int v0 = 0, v1 = 0, v2 = 0, v3 = 0;
    if (base + 0 < n) v0 = cnt[base + 0];
    if (base + 1 < n) v1 = cnt[base + 1];
    if (base + 2 < n) v2 = cnt[base + 2];
    if (base + 3 < n) v3 = cnt[base + 3];
    int s = v0 + v1 + v2 + v3;
    lds[t] = s;
    __syncthreads();
    for (int off = 1; off < 256; off <<= 1) {
        int x = 0;
        if (t >= off) x = lds[t - off];
        __syncthreads();
        if (t >= off) lds[t] += x;
        __syncthreads();
    }
    int excl = lds[t] - s;
    if (t == 255) blockSums[blockIdx.x] = lds[255];
    if (base + 0 < n) pre[base + 0] = excl;
    if (base + 1 < n) pre[base + 1] = excl + v0;
    if (base + 2 < n) pre[base + 2] = excl + v0 + v1;
    if (base + 3 < n) pre[base + 3] = excl + v0 + v1 + v2;
}

__global__ void scan2_kernel(int* __restrict__ blockSums, int nb) {
    if (threadIdx.x == 0 && blockIdx.x == 0) {
        int acc = 0;
        for (int i = 0; i < nb; ++i) { int v = blockSums[i]; blockSums[i] = acc; acc += v; }
    }
}

__global__ __launch_bounds__(256) void scan3_kernel(int* __restrict__ pre,
                                                    const int* __restrict__ blockSums,
                                                    int* __restrict__ cursor, int n, int nE) {
    int i = blockIdx.x * 256 + threadIdx.x;
    if (i < n) {
        int v = pre[i] + blockSums[i / SCAN_BLK];
        pre[i] = v;
        cursor[i] = v;
    }
    if (i == 0) pre[n] = nE;
}

__global__ __launch_bounds__(256) void scatter_kernel(const int* __restrict__ ei,
                                                      int* __restrict__ cursor,
                                                      int* __restrict__ srcIdx, int nE) {
    int e = blockIdx.x * 256 + threadIdx.x;
    if (e >= nE) return;
    int dst = ei[nE + e];
    int pos = atomicAdd(&cursor[dst], 1);
    srcIdx[pos] = ei[e];
}

// ---- alpha1: per node compute alpha_src/alpha_dst (4 heads), h1 fp16 ----
__global__ __launch_bounds__(256) void alpha1_kernel(const h16* __restrict__ h1,
                                                     const float* __restrict__ a_src,
                                                     const float* __restrict__ a_dst,
                                                     float* __restrict__ as1,
                                                     float* __restrict__ ad1, int n) {
    const int lane = threadIdx.x & 63;
    const int node = (blockIdx.x * 256 + threadIdx.x) >> 6;
    if (node >= n) return;
    const int hh = lane >> 4;
    const int c0 = (lane & 15) * 4;
    half4v hv4 = *(const half4v*)&h1[(size_t)node * D1 + lane * 4];
    float4 hv = make_float4((float)hv4.x, (float)hv4.y, (float)hv4.z, (float)hv4.w);
    float4 av = *(const float4*)&a_src[hh * HID + c0];
    float4 bv = *(const float4*)&a_dst[hh * HID + c0];
    float ps = hv.x * av.x + hv.y * av.y + hv.z * av.z + hv.w * av.w;
    float pd = hv.x * bv.x + hv.y * bv.y + hv.z * bv.z + hv.w * bv.w;
    #pragma unroll
    for (int off = 1; off < 16; off <<= 1) {
        ps += __shfl_xor(ps, off, 64);
        pd += __shfl_xor(pd, off, 64);
    }
    if ((lane & 15) == 0) {
        as1[node * 4 + hh] = ps;
        ad1[node * 4 + hh] = pd;
    }
}

// ---- gather1: wave per dst node; 4-edge unroll; fused bias+LN+LeakyReLU ----
__global__ __launch_bounds__(256) void gather1_kernel(const h16* __restrict__ h1,
                                                      const float* __restrict__ as1,
                                                      const float* __restrict__ ad1,
                                                      const int* __restrict__ rowStart,
                                                      const int* __restrict__ srcIdx,
                                                      const float* __restrict__ b1,
                                                      const float* __restrict__ gamma,
                                                      const float* __restrict__ beta,
                                                      float* __restrict__ hmid, int n) {
    const int lane = threadIdx.x & 63;
    const int node = (blockIdx.x * 256 + threadIdx.x) >> 6;
    if (node >= n) return;
    const int hh = lane >> 4;
    const float ad_n = ad1[node * 4 + hh];
    const float as_n = as1[node * 4 + hh];
    half4v sv = *(const half4v*)&h1[(size_t)node * D1 + lane * 4];
    float w = expf(lrelu02(as_n + ad_n));           // self-loop
    float4 acc = make_float4((float)sv.x * w, (float)sv.y * w,
                             (float)sv.z * w, (float)sv.w * w);
    float den = w;
    const int beg = rowStart[node], end = rowStart[node + 1];
    int j = beg;
    for (; j + 3 < end; j += 4) {
        int s0 = srcIdx[j + 0];
        int s1 = srcIdx[j + 1];
        int s2 = srcIdx[j + 2];
        int s3 = srcIdx[j + 3];
        float l0 = as1[s0 * 4 + hh];
        float l1 = as1[s1 * 4 + hh];
        float l2 = as1[s2 * 4 + hh];
        float l3 = as1[s3 * 4 + hh];
        half4v r0 = *(const half4v*)&h1[(size_t)s0 * D1 + lane * 4];
        half4v r1 = *(const half4v*)&h1[(size_t)s1 * D1 + lane * 4];
        half4v r2 = *(const half4v*)&h1[(size_t)s2 * D1 + lane * 4];
        half4v r3 = *(const half4v*)&h1[(size_t)s3 * D1 + lane * 4];
        float w0 = expf(lrelu02(l0 + ad_n));
        float w1 = expf(lrelu02(l1 + ad_n));
        float w2 = expf(lrelu02(l2 + ad_n));
        float w3 = expf(lrelu02(l3 + ad_n));
        acc.x = fmaf((float)r0.x, w0, acc.x); acc.y = fmaf((float)r0.y, w0, acc.y);
        acc.z = fmaf((float)r0.z, w0, acc.z); acc.w = fmaf((float)r0.w, w0, acc.w);
        acc.x = fmaf((float)r1.x, w1, acc.x); acc.y = fmaf((float)r1.y, w1, acc.y);
        acc.z = fmaf((float)r1.z, w1, acc.z); acc.w = fmaf((float)r1.w, w1, acc.w);
        acc.x = fmaf((float)r2.x, w2, acc.x); acc.y = fmaf((float)r2.y, w2, acc.y);
        acc.z = fmaf((float)r2.z, w2, acc.z); acc.w = fmaf((float)r2.w, w2, acc.w);
        acc.x = fmaf((float)r3.x, w3, acc.x); acc.y = fmaf((float)r3.y, w3, acc.y);
        acc.z = fmaf((float)r3.z, w3, acc.z); acc.w = fmaf((float)r3.w, w3, acc.w);
        den += w0 + w1 + w2 + w3;
    }
    for (; j < end; ++j) {
        int s = srcIdx[j];
        float wj = expf(lrelu02(as1[s * 4 + hh] + ad_n));
        half4v xv = *(const half4v*)&h1[(size_t)s * D1 + lane * 4];
        acc.x = fmaf((float)xv.x, wj, acc.x);
        acc.y = fmaf((float)xv.y, wj, acc.y);
        acc.z = fmaf((float)xv.z, wj, acc.z);
        acc.w = fmaf((float)xv.w, wj, acc.w);
        den += wj;
    }
    float inv = 1.f / (den + 1e-16f);
    float4 bv = *(const float4*)&b1[lane * 4];
    float4 y;
    y.x = acc.x * inv + bv.x; y.y = acc.y * inv + bv.y;
    y.z = acc.z * inv + bv.z; y.w = acc.w * inv + bv.w;
    float s = y.x + y.y + y.z + y.w;
    #pragma unroll
    for (int off = 1; off < 64; off <<= 1) s += __shfl_xor(s, off, 64);
    float mu = s * (1.f / 256.f);
    float4 dx;
    dx.x = y.x - mu; dx.y = y.y - mu; dx.z = y.z - mu; dx.w = y.w - mu;
    float sq = dx.x * dx.x + dx.y * dx.y + dx.z * dx.z + dx.w * dx.w;
    #pragma unroll
    for (int off = 1; off < 64; off <<= 1) sq += __shfl_xor(sq, off, 64);
    float rs = rsqrtf(sq * (1.f / 256.f) + 1e-5f);
    float4 g = *(const float4*)&gamma[lane * 4];
    float4 be = *(const float4*)&beta[lane * 4];
    float4 o;
    o.x = lrelu001(dx.x * rs * g.x + be.x);
    o.y = lrelu001(dx.y * rs * g.y + be.y);
    o.z = lrelu001(dx.z * rs * g.z + be.z);
    o.w = lrelu001(dx.w * rs * g.w + be.w);
    *(float4*)&hmid[(size_t)node * D1 + lane * 4] = o;
}

// ---- alpha2: per node alpha for layer 2 (1 head), h2 fp16 ----
__global__ __launch_bounds__(256) void alpha2_kernel(const h16* __restrict__ h2,
                                                     const float* __restrict__ a_src,
                                                     const float* __restrict__ a_dst,
                                                     float* __restrict__ as2,
                                                     float* __restrict__ ad2, int n) {
    const int lane = threadIdx.x & 63;
    const int node = (blockIdx.x * 256 + threadIdx.x) >> 6;
    if (node >= n) return;
    float v = (float)h2[(size_t)node * HID + lane];
    float ps = v * a_src[lane];
    float pd = v * a_dst[lane];
    #pragma unroll
    for (int off = 1; off < 64; off <<= 1) {
        ps += __shfl_xor(ps, off, 64);
        pd += __shfl_xor(pd, off, 64);
    }
    if (lane == 0) { as2[node] = ps; ad2[node] = pd; }
}

// ---- gather2: wave per dst node (1 head x 64 ch); 4-edge unroll; fused bias ----
__global__ __launch_bounds__(256) void gather2_kernel(const h16* __restrict__ h2,
                                                      const float* __restrict__ as2,
                                                      const float* __restrict__ ad2,
                                                      const int* __restrict__ rowStart,
                                                      const int* __restrict__ srcIdx,
                                                      const float* __restrict__ b2,
                                                      float* __restrict__ out, int n) {
    const int lane = threadIdx.x & 63;
    const int node = (blockIdx.x * 256 + threadIdx.x) >> 6;
    if (node >= n) return;
    const float ad_n = ad2[node];
    float v = (float)h2[(size_t)node * HID + lane];
    float w = expf(lrelu02(as2[node] + ad_n));      // self-loop
    float acc = v * w;
    float den = w;
    const int beg = rowStart[node], end = rowStart[node + 1];
    int j = beg;
    for (; j + 3 < end; j += 4) {
        int s0 = srcIdx[j + 0];
        int s1 = srcIdx[j + 1];
        int s2 = srcIdx[j + 2];
        int s3 = srcIdx[j + 3];
        float l0 = as2[s0], l1 = as2[s1], l2 = as2[s2], l3 = as2[s3];
        float v0 = (float)h2[(size_t)s0 * HID + lane];
        float v1 = (float)h2[(size_t)s1 * HID + lane];
        float v2 = (float)h2[(size_t)s2 * HID + lane];
        float v3 = (float)h2[(size_t)s3 * HID + lane];
        float w0 = expf(lrelu02(l0 + ad_n));
        float w1 = expf(lrelu02(l1 + ad_n));
        float w2 = expf(lrelu02(l2 + ad_n));
        float w3 = expf(lrelu02(l3 + ad_n));
        acc = fmaf(v0, w0, acc);
        acc = fmaf(v1, w1, acc);
        acc = fmaf(v2, w2, acc);
        acc = fmaf(v3, w3, acc);
        den += w0 + w1 + w2 + w3;
    }
    for (; j < end; ++j) {
        int s = srcIdx[j];
        float wj = expf(lrelu02(as2[s] + ad_n));
        acc = fmaf((float)h2[(size_t)s * HID + lane], wj, acc);
        den += wj;
    }
    out[(size_t)node * HID + lane] = acc / (den + 1e-16f) + b2[lane];
}

extern "C" void kernel_launch(void* const* d_in, const int* in_sizes, int n_in,
                              void* d_out, int out_size, void* d_ws, size_t ws_size,
                              hipStream_t stream) {
    const float* x      = (const float*)d_in[0];
    const int*   ei     = (const int*)d_in[1];
    const float* W1     = (const float*)d_in[2];
    const float* a_src1 = (const float*)d_in[3];
    const float* a_dst1 = (const float*)d_in[4];
    const float* b1     = (const float*)d_in[5];
    const float* gamma  = (const float*)d_in[6];
    const float* beta   = (const float*)d_in[7];
    const float* W2     = (const float*)d_in[8];
    const float* a_src2 = (const float*)d_in[9];
    const float* a_dst2 = (const float*)d_in[10];
    const float* b2     = (const float*)d_in[11];
    float* out = (float*)d_out;

    const int N = in_sizes[0] / IN_CH;
    const int E = in_sizes[1] / 2;

    // workspace layout (in float slots)
    float* ws = (float*)d_ws;
    h16*   h1   = (h16*)ws;                          // N*256 halfs  = 128N floats
    float* hmid = ws + (size_t)128 * N;              // N*256 floats
    h16*   h2   = (h16*)(ws + (size_t)384 * N);      // N*64 halfs   = 32N floats
    float* as1  = ws + (size_t)416 * N;              // 4N
    float* ad1  = as1 + (size_t)4 * N;               // 4N
    float* as2  = ad1 + (size_t)4 * N;               // N
    float* ad2  = as2 + N;                           // N
    int* rowStart  = (int*)(ad2 + N);                // N+1
    int* cursor    = rowStart + N + 1;               // N
    int* srcIdx    = cursor + N;                     // E
    int* blockSums = srcIdx + E;                     // ~64

    const int nodeBlocks = (N + 3) / 4;
    const int nThreadBlocksN = (N + 255) / 256;
    const int nThreadBlocksE = (E + 255) / 256;
    const int scanBlocks = (N + SCAN_BLK - 1) / SCAN_BLK;

    // CSR build (by destination)
    zero_kernel<<<nThreadBlocksN, 256, 0, stream>>>(cursor, N);
    hist_kernel<<<nThreadBlocksE, 256, 0, stream>>>(ei, cursor, E);
    scan1_kernel<<<scanBlocks, 256, 0, stream>>>(cursor, rowStart, blockSums, N);
    scan2_kernel<<<1, 64, 0, stream>>>(blockSums, scanBlocks);
    scan3_kernel<<<nThreadBlocksN, 256, 0, stream>>>(rowStart, blockSums, cursor, N, E);
    scatter_kernel<<<nThreadBlocksE, 256, 0, stream>>>(ei, cursor, srcIdx, E);

    // layer 1
    gemm1_kernel<<<(N + 31) / 32, 256, 0, stream>>>(x, W1, h1, N);
    alpha1_kernel<<<nodeBlocks, 256, 0, stream>>>(h1, a_src1, a_dst1, as1, ad1, N);
    gather1_kernel<<<nodeBlocks, 256, 0, stream>>>(h1, as1, ad1, rowStart, srcIdx,
                                                   b1, gamma, beta, hmid, N);
    // layer 2
    gemm2_kernel<<<(N + 31) / 32, 256, 0, stream>>>(hmid, W2, h2, N);
    alpha2_kernel<<<nodeBlocks, 256, 0, stream>>>(h2, a_src2, a_dst2, as2, ad2, N);
    gather2_kernel<<<nodeBlocks, 256, 0, stream>>>(h2, as2, ad2, rowStart, srcIdx,
                                                   b2, out, N);
}

// Round 4
// 304.032 us; speedup vs baseline: 10.1582x; 1.1840x over previous
//
#include <hip/hip_runtime.h>
#include <hip/hip_bf16.h>

#define IN_CH 128
#define D1 256      // HEADS*HID
#define HID 64
#define HEADS 4
#define SCAN_BLK 1024

typedef _Float16 h16;
typedef __attribute__((ext_vector_type(4))) _Float16 half4v;
typedef __attribute__((ext_vector_type(8))) _Float16 half8v;
typedef __attribute__((ext_vector_type(4))) float f32x4;

__device__ __forceinline__ float lrelu02(float v) { return v > 0.f ? v : 0.2f * v; }
__device__ __forceinline__ float lrelu001(float v) { return v > 0.f ? v : 0.01f * v; }

// ---- cast x -> fp16 (padded rows zeroed) ----
__global__ __launch_bounds__(256) void castx_kernel(const float* __restrict__ x,
                                                    h16* __restrict__ xh,
                                                    long total, long valid) {
    long i = ((long)blockIdx.x * 256 + threadIdx.x) * 4;
    if (i >= total) return;
    float4 v = make_float4(0.f, 0.f, 0.f, 0.f);
    if (i < valid) v = *(const float4*)&x[i];   // chunks are 4-aligned; valid%4==0
    half4v o; o.x = (h16)v.x; o.y = (h16)v.y; o.z = (h16)v.z; o.w = (h16)v.w;
    *(half4v*)&xh[i] = o;
}

// ---- cast + transpose weights: W1[128,256]->W1t[256,128], W2[256,64]->W2t[64,256] ----
__global__ __launch_bounds__(256) void castw_kernel(const float* __restrict__ W1,
                                                    const float* __restrict__ W2,
                                                    h16* __restrict__ w1t,
                                                    h16* __restrict__ w2t) {
    const int t = threadIdx.x;
    if (blockIdx.x == 0) {
        for (int k = 0; k < IN_CH; ++k) w1t[t * IN_CH + k] = (h16)W1[k * D1 + t];
    } else if (t < HID) {
        for (int k = 0; k < D1; ++k) w2t[t * D1 + k] = (h16)W2[k * HID + t];
    }
}

// ---- MFMA GEMM1: h1[N,256](fp16) = xh[N,128] @ W1 (via W1t) ----
__global__ __launch_bounds__(256) void gemm1_mfma(const h16* __restrict__ xh,
                                                  const h16* __restrict__ w1t,
                                                  h16* __restrict__ h1, int n) {
    const int wave = threadIdx.x >> 6, lane = threadIdx.x & 63;
    const int r = lane & 15, ksel = lane >> 4;
    const int rowBase = blockIdx.x * 64 + wave * 16;
    const h16* xrow = xh + (size_t)(rowBase + r) * IN_CH + ksel * 8;
    half8v a[4];
    #pragma unroll
    for (int kk = 0; kk < 4; ++kk) a[kk] = *(const half8v*)(xrow + kk * 32);
    f32x4 acc[16];
    #pragma unroll
    for (int ct = 0; ct < 16; ++ct) acc[ct] = (f32x4){0.f, 0.f, 0.f, 0.f};
    #pragma unroll
    for (int ct = 0; ct < 16; ++ct) {
        const h16* wrow = w1t + (size_t)(ct * 16 + r) * IN_CH + ksel * 8;
        #pragma unroll
        for (int kk = 0; kk < 4; ++kk) {
            half8v b = *(const half8v*)(wrow + kk * 32);
            acc[ct] = __builtin_amdgcn_mfma_f32_16x16x32_f16(a[kk], b, acc[ct], 0, 0, 0);
        }
    }
    #pragma unroll
    for (int i = 0; i < 4; ++i) {
        int row = rowBase + ksel * 4 + i;
        if (row < n) {
            #pragma unroll
            for (int ct = 0; ct < 16; ++ct)
                h1[(size_t)row * D1 + ct * 16 + r] = (h16)acc[ct][i];
        }
    }
}

// ---- MFMA GEMM2: h2[N,64](fp16) = hmid[N,256] @ W2 (via W2t) ----
__global__ __launch_bounds__(256) void gemm2_mfma(const h16* __restrict__ hm,
                                                  const h16* __restrict__ w2t,
                                                  h16* __restrict__ h2, int n) {
    const int wave = threadIdx.x >> 6, lane = threadIdx.x & 63;
    const int r = lane & 15, ksel = lane >> 4;
    const int rowBase = blockIdx.x * 64 + wave * 16;
    const h16* xrow = hm + (size_t)(rowBase + r) * D1 + ksel * 8;
    half8v a[8];
    #pragma unroll
    for (int kk = 0; kk < 8; ++kk) a[kk] = *(const half8v*)(xrow + kk * 32);
    f32x4 acc[4];
    #pragma unroll
    for (int ct = 0; ct < 4; ++ct) acc[ct] = (f32x4){0.f, 0.f, 0.f, 0.f};
    #pragma unroll
    for (int ct = 0; ct < 4; ++ct) {
        const h16* wrow = w2t + (size_t)(ct * 16 + r) * D1 + ksel * 8;
        #pragma unroll
        for (int kk = 0; kk < 8; ++kk) {
            half8v b = *(const half8v*)(wrow + kk * 32);
            acc[ct] = __builtin_amdgcn_mfma_f32_16x16x32_f16(a[kk], b, acc[ct], 0, 0, 0);
        }
    }
    #pragma unroll
    for (int i = 0; i < 4; ++i) {
        int row = rowBase + ksel * 4 + i;
        if (row < n) {
            #pragma unroll
            for (int ct = 0; ct < 4; ++ct)
                h2[(size_t)row * HID + ct * 16 + r] = (h16)acc[ct][i];
        }
    }
}

// ================= CSR build (by destination) =================
__global__ __launch_bounds__(256) void zero_kernel(int* __restrict__ cnt, int n) {
    int i = blockIdx.x * 256 + threadIdx.x;
    if (i < n) cnt[i] = 0;
}

__global__ __launch_bounds__(256) void hist_kernel(const int* __restrict__ ei,
                                                   int* __restrict__ cnt, int nE) {
    int e = blockIdx.x * 256 + threadIdx.x;
    if (e >= nE) return;
    atomicAdd(&cnt[ei[nE + e]], 1);
}

__global__ __launch_bounds__(256) void scan1_kernel(const int* __restrict__ cnt,
                                                    int* __restrict__ pre,
                                                    int* __restrict__ blockSums, int n) {
    __shared__ int lds[256];
    const int t = threadIdx.x;
    const int base = blockIdx.x * SCAN_BLK + t * 4;
    int v0 = 0, v1 = 0, v2 = 0, v3 = 0;
    if (base + 0 < n) v0 = cnt[base + 0];
    if (base + 1 < n) v1 = cnt[base + 1];
    if (base + 2 < n) v2 = cnt[base + 2];
    if (base + 3 < n) v3 = cnt[base + 3];
    int s = v0 + v1 + v2 + v3;
    lds[t] = s;
    __syncthreads();
    for (int off = 1; off < 256; off <<= 1) {
        int x = 0;
        if (t >= off) x = lds[t - off];
        __syncthreads();
        if (t >= off) lds[t] += x;
        __syncthreads();
    }
    int excl = lds[t] - s;
    if (t == 255) blockSums[blockIdx.x] = lds[255];
    if (base + 0 < n) pre[base + 0] = excl;
    if (base + 1 < n) pre[base + 1] = excl + v0;
    if (base + 2 < n) pre[base + 2] = excl + v0 + v1;
    if (base + 3 < n) pre[base + 3] = excl + v0 + v1 + v2;
}

__global__ void scan2_kernel(int* __restrict__ blockSums, int nb) {
    if (threadIdx.x == 0 && blockIdx.x == 0) {
        int acc = 0;
        for (int i = 0; i < nb; ++i) { int v = blockSums[i]; blockSums[i] = acc; acc += v; }
    }
}

__global__ __launch_bounds__(256) void scan3_kernel(int* __restrict__ pre,
                                                    const int* __restrict__ blockSums,
                                                    int* __restrict__ cursor, int n, int nE) {
    int i = blockIdx.x * 256 + threadIdx.x;
    if (i < n) {
        int v = pre[i] + blockSums[i / SCAN_BLK];
        pre[i] = v;
        cursor[i] = v;
    }
    if (i == 0) pre[n] = nE;
}

__global__ __launch_bounds__(256) void scatter_kernel(const int* __restrict__ ei,
                                                      int* __restrict__ cursor,
                                                      int* __restrict__ srcIdx, int nE) {
    int e = blockIdx.x * 256 + threadIdx.x;
    if (e >= nE) return;
    int dst = ei[nE + e];
    int pos = atomicAdd(&cursor[dst], 1);
    srcIdx[pos] = ei[e];
}

// ---- alpha1: per node alpha_src/alpha_dst (4 heads), h1 fp16 ----
__global__ __launch_bounds__(256) void alpha1_kernel(const h16* __restrict__ h1,
                                                     const float* __restrict__ a_src,
                                                     const float* __restrict__ a_dst,
                                                     float* __restrict__ as1,
                                                     float* __restrict__ ad1, int n) {
    const int lane = threadIdx.x & 63;
    const int node = (blockIdx.x * 256 + threadIdx.x) >> 6;
    if (node >= n) return;
    const int hh = lane >> 4;
    const int c0 = (lane & 15) * 4;
    half4v hv4 = *(const half4v*)&h1[(size_t)node * D1 + lane * 4];
    float4 hv = make_float4((float)hv4.x, (float)hv4.y, (float)hv4.z, (float)hv4.w);
    float4 av = *(const float4*)&a_src[hh * HID + c0];
    float4 bv = *(const float4*)&a_dst[hh * HID + c0];
    float ps = hv.x * av.x + hv.y * av.y + hv.z * av.z + hv.w * av.w;
    float pd = hv.x * bv.x + hv.y * bv.y + hv.z * bv.z + hv.w * bv.w;
    #pragma unroll
    for (int off = 1; off < 16; off <<= 1) {
        ps += __shfl_xor(ps, off, 64);
        pd += __shfl_xor(pd, off, 64);
    }
    if ((lane & 15) == 0) {
        as1[node * 4 + hh] = ps;
        ad1[node * 4 + hh] = pd;
    }
}

// ---- gather1: wave per dst node; fused bias+LN+LeakyReLU; fp16 out ----
__global__ __launch_bounds__(256) void gather1_kernel(const h16* __restrict__ h1,
                                                      const float* __restrict__ as1,
                                                      const float* __restrict__ ad1,
                                                      const int* __restrict__ rowStart,
                                                      const int* __restrict__ srcIdx,
                                                      const float* __restrict__ b1,
                                                      const float* __restrict__ gamma,
                                                      const float* __restrict__ beta,
                                                      h16* __restrict__ hmid, int n, int npad) {
    const int lane = threadIdx.x & 63;
    const int node = (blockIdx.x * 256 + threadIdx.x) >> 6;
    if (node >= npad) return;
    if (node >= n) {            // zero pad rows (gemm2 reads them)
        half4v z = {(h16)0.f, (h16)0.f, (h16)0.f, (h16)0.f};
        *(half4v*)&hmid[(size_t)node * D1 + lane * 4] = z;
        return;
    }
    const int hh = lane >> 4;
    const float ad_n = ad1[node * 4 + hh];
    const float as_n = as1[node * 4 + hh];
    half4v sv = *(const half4v*)&h1[(size_t)node * D1 + lane * 4];
    float w = expf(lrelu02(as_n + ad_n));           // self-loop
    float4 acc = make_float4((float)sv.x * w, (float)sv.y * w,
                             (float)sv.z * w, (float)sv.w * w);
    float den = w;
    const int beg = rowStart[node], end = rowStart[node + 1];
    int j = beg;
    for (; j + 3 < end; j += 4) {
        int s0 = srcIdx[j + 0];
        int s1 = srcIdx[j + 1];
        int s2 = srcIdx[j + 2];
        int s3 = srcIdx[j + 3];
        float l0 = as1[s0 * 4 + hh];
        float l1 = as1[s1 * 4 + hh];
        float l2 = as1[s2 * 4 + hh];
        float l3 = as1[s3 * 4 + hh];
        half4v r0 = *(const half4v*)&h1[(size_t)s0 * D1 + lane * 4];
        half4v r1 = *(const half4v*)&h1[(size_t)s1 * D1 + lane * 4];
        half4v r2 = *(const half4v*)&h1[(size_t)s2 * D1 + lane * 4];
        half4v r3 = *(const half4v*)&h1[(size_t)s3 * D1 + lane * 4];
        float w0 = expf(lrelu02(l0 + ad_n));
        float w1 = expf(lrelu02(l1 + ad_n));
        float w2 = expf(lrelu02(l2 + ad_n));
        float w3 = expf(lrelu02(l3 + ad_n));
        acc.x = fmaf((float)r0.x, w0, acc.x); acc.y = fmaf((float)r0.y, w0, acc.y);
        acc.z = fmaf((float)r0.z, w0, acc.z); acc.w = fmaf((float)r0.w, w0, acc.w);
        acc.x = fmaf((float)r1.x, w1, acc.x); acc.y = fmaf((float)r1.y, w1, acc.y);
        acc.z = fmaf((float)r1.z, w1, acc.z); acc.w = fmaf((float)r1.w, w1, acc.w);
        acc.x = fmaf((float)r2.x, w2, acc.x); acc.y = fmaf((float)r2.y, w2, acc.y);
        acc.z = fmaf((float)r2.z, w2, acc.z); acc.w = fmaf((float)r2.w, w2, acc.w);
        acc.x = fmaf((float)r3.x, w3, acc.x); acc.y = fmaf((float)r3.y, w3, acc.y);
        acc.z = fmaf((float)r3.z, w3, acc.z); acc.w = fmaf((float)r3.w, w3, acc.w);
        den += w0 + w1 + w2 + w3;
    }
    for (; j < end; ++j) {
        int s = srcIdx[j];
        float wj = expf(lrelu02(as1[s * 4 + hh] + ad_n));
        half4v xv = *(const half4v*)&h1[(size_t)s * D1 + lane * 4];
        acc.x = fmaf((float)xv.x, wj, acc.x);
        acc.y = fmaf((float)xv.y, wj, acc.y);
        acc.z = fmaf((float)xv.z, wj, acc.z);
        acc.w = fmaf((float)xv.w, wj, acc.w);
        den += wj;
    }
    float inv = 1.f / (den + 1e-16f);
    float4 bv = *(const float4*)&b1[lane * 4];
    float4 y;
    y.x = acc.x * inv + bv.x; y.y = acc.y * inv + bv.y;
    y.z = acc.z * inv + bv.z; y.w = acc.w * inv + bv.w;
    float s = y.x + y.y + y.z + y.w;
    #pragma unroll
    for (int off = 1; off < 64; off <<= 1) s += __shfl_xor(s, off, 64);
    float mu = s * (1.f / 256.f);
    float4 dx;
    dx.x = y.x - mu; dx.y = y.y - mu; dx.z = y.z - mu; dx.w = y.w - mu;
    float sq = dx.x * dx.x + dx.y * dx.y + dx.z * dx.z + dx.w * dx.w;
    #pragma unroll
    for (int off = 1; off < 64; off <<= 1) sq += __shfl_xor(sq, off, 64);
    float rs = rsqrtf(sq * (1.f / 256.f) + 1e-5f);
    float4 g = *(const float4*)&gamma[lane * 4];
    float4 be = *(const float4*)&beta[lane * 4];
    half4v o;
    o.x = (h16)lrelu001(dx.x * rs * g.x + be.x);
    o.y = (h16)lrelu001(dx.y * rs * g.y + be.y);
    o.z = (h16)lrelu001(dx.z * rs * g.z + be.z);
    o.w = (h16)lrelu001(dx.w * rs * g.w + be.w);
    *(half4v*)&hmid[(size_t)node * D1 + lane * 4] = o;
}

// ---- alpha2 ----
__global__ __launch_bounds__(256) void alpha2_kernel(const h16* __restrict__ h2,
                                                     const float* __restrict__ a_src,
                                                     const float* __restrict__ a_dst,
                                                     float* __restrict__ as2,
                                                     float* __restrict__ ad2, int n) {
    const int lane = threadIdx.x & 63;
    const int node = (blockIdx.x * 256 + threadIdx.x) >> 6;
    if (node >= n) return;
    float v = (float)h2[(size_t)node * HID + lane];
    float ps = v * a_src[lane];
    float pd = v * a_dst[lane];
    #pragma unroll
    for (int off = 1; off < 64; off <<= 1) {
        ps += __shfl_xor(ps, off, 64);
        pd += __shfl_xor(pd, off, 64);
    }
    if (lane == 0) { as2[node] = ps; ad2[node] = pd; }
}

// ---- gather2 ----
__global__ __launch_bounds__(256) void gather2_kernel(const h16* __restrict__ h2,
                                                      const float* __restrict__ as2,
                                                      const float* __restrict__ ad2,
                                                      const int* __restrict__ rowStart,
                                                      const int* __restrict__ srcIdx,
                                                      const float* __restrict__ b2,
                                                      float* __restrict__ out, int n) {
    const int lane = threadIdx.x & 63;
    const int node = (blockIdx.x * 256 + threadIdx.x) >> 6;
    if (node >= n) return;
    const float ad_n = ad2[node];
    float v = (float)h2[(size_t)node * HID + lane];
    float w = expf(lrelu02(as2[node] + ad_n));      // self-loop
    float acc = v * w;
    float den = w;
    const int beg = rowStart[node], end = rowStart[node + 1];
    int j = beg;
    for (; j + 3 < end; j += 4) {
        int s0 = srcIdx[j + 0];
        int s1 = srcIdx[j + 1];
        int s2 = srcIdx[j + 2];
        int s3 = srcIdx[j + 3];
        float l0 = as2[s0], l1 = as2[s1], l2 = as2[s2], l3 = as2[s3];
        float v0 = (float)h2[(size_t)s0 * HID + lane];
        float v1 = (float)h2[(size_t)s1 * HID + lane];
        float v2 = (float)h2[(size_t)s2 * HID + lane];
        float v3 = (float)h2[(size_t)s3 * HID + lane];
        float w0 = expf(lrelu02(l0 + ad_n));
        float w1 = expf(lrelu02(l1 + ad_n));
        float w2 = expf(lrelu02(l2 + ad_n));
        float w3 = expf(lrelu02(l3 + ad_n));
        acc = fmaf(v0, w0, acc);
        acc = fmaf(v1, w1, acc);
        acc = fmaf(v2, w2, acc);
        acc = fmaf(v3, w3, acc);
        den += w0 + w1 + w2 + w3;
    }
    for (; j < end; ++j) {
        int s = srcIdx[j];
        float wj = expf(lrelu02(as2[s] + ad_n));
        acc = fmaf((float)h2[(size_t)s * HID + lane], wj, acc);
        den += wj;
    }
    out[(size_t)node * HID + lane] = acc / (den + 1e-16f) + b2[lane];
}

extern "C" void kernel_launch(void* const* d_in, const int* in_sizes, int n_in,
                              void* d_out, int out_size, void* d_ws, size_t ws_size,
                              hipStream_t stream) {
    const float* x      = (const float*)d_in[0];
    const int*   ei     = (const int*)d_in[1];
    const float* W1     = (const float*)d_in[2];
    const float* a_src1 = (const float*)d_in[3];
    const float* a_dst1 = (const float*)d_in[4];
    const float* b1     = (const float*)d_in[5];
    const float* gamma  = (const float*)d_in[6];
    const float* beta   = (const float*)d_in[7];
    const float* W2     = (const float*)d_in[8];
    const float* a_src2 = (const float*)d_in[9];
    const float* a_dst2 = (const float*)d_in[10];
    const float* b2     = (const float*)d_in[11];
    float* out = (float*)d_out;

    const int N = in_sizes[0] / IN_CH;
    const int E = in_sizes[1] / 2;
    const int NP = (N + 63) & ~63;          // row-pad for 64-row MFMA tiles

    // workspace layout (float slots)
    float* ws = (float*)d_ws;
    h16*   h1   = (h16*)ws;                                  // N*256 halfs
    h16*   xh   = (h16*)(ws + (size_t)128 * N);              // NP*128 halfs
    h16*   hmid = (h16*)(ws + (size_t)128 * N + 64 * NP);    // NP*256 halfs
    h16*   h2   = (h16*)(ws + (size_t)128 * N + 192 * NP);   // N*64 halfs
    float* fbase = ws + (size_t)160 * N + 192 * NP;
    h16*   w1t  = (h16*)fbase;                               // 32768 halfs = 16384 f
    h16*   w2t  = (h16*)(fbase + 16384);                     // 16384 halfs = 8192 f
    float* as1  = fbase + 16384 + 8192;                      // 4N
    float* ad1  = as1 + (size_t)4 * N;                       // 4N
    float* as2  = ad1 + (size_t)4 * N;                       // N
    float* ad2  = as2 + N;                                   // N
    int* rowStart  = (int*)(ad2 + N);                        // N+1
    int* cursor    = rowStart + N + 1;                       // N
    int* srcIdx    = cursor + N;                             // E
    int* blockSums = srcIdx + E;                             // ~64

    const int nodeBlocks  = (N + 3) / 4;
    const int nodeBlocksP = (NP + 3) / 4;
    const int nThreadBlocksN = (N + 255) / 256;
    const int nThreadBlocksE = (E + 255) / 256;
    const int scanBlocks = (N + SCAN_BLK - 1) / SCAN_BLK;

    // casts
    castx_kernel<<<(NP * IN_CH / 4 + 255) / 256, 256, 0, stream>>>(
        x, xh, (long)NP * IN_CH, (long)N * IN_CH);
    castw_kernel<<<2, 256, 0, stream>>>(W1, W2, w1t, w2t);

    // CSR build (by destination)
    zero_kernel<<<nThreadBlocksN, 256, 0, stream>>>(cursor, N);
    hist_kernel<<<nThreadBlocksE, 256, 0, stream>>>(ei, cursor, E);
    scan1_kernel<<<scanBlocks, 256, 0, stream>>>(cursor, rowStart, blockSums, N);
    scan2_kernel<<<1, 64, 0, stream>>>(blockSums, scanBlocks);
    scan3_kernel<<<nThreadBlocksN, 256, 0, stream>>>(rowStart, blockSums, cursor, N, E);
    scatter_kernel<<<nThreadBlocksE, 256, 0, stream>>>(ei, cursor, srcIdx, E);

    // layer 1
    gemm1_mfma<<<NP / 64, 256, 0, stream>>>(xh, w1t, h1, N);
    alpha1_kernel<<<nodeBlocks, 256, 0, stream>>>(h1, a_src1, a_dst1, as1, ad1, N);
    gather1_kernel<<<nodeBlocksP, 256, 0, stream>>>(h1, as1, ad1, rowStart, srcIdx,
                                                    b1, gamma, beta, hmid, N, NP);
    // layer 2
    gemm2_mfma<<<NP / 64, 256, 0, stream>>>(hmid, w2t, h2, N);
    alpha2_kernel<<<nodeBlocks, 256, 0, stream>>>(h2, a_src2, a_dst2, as2, ad2, N);
    gather2_kernel<<<nodeBlocks, 256, 0, stream>>>(h2, as2, ad2, rowStart, srcIdx,
                                                   b2, out, N);
}

// Round 5
// 293.369 us; speedup vs baseline: 10.5274x; 1.0363x over previous
//
#include <hip/hip_runtime.h>
#include <hip/hip_bf16.h>

#define IN_CH 128
#define D1 256      // HEADS*HID
#define HID 64
#define HEADS 4
#define SCAN_BLK 1024

typedef _Float16 h16;
typedef __attribute__((ext_vector_type(4))) _Float16 half4v;
typedef __attribute__((ext_vector_type(8))) _Float16 half8v;
typedef __attribute__((ext_vector_type(4))) float f32x4;

__device__ __forceinline__ float lrelu02(float v) { return v > 0.f ? v : 0.2f * v; }
__device__ __forceinline__ float lrelu001(float v) { return v > 0.f ? v : 0.01f * v; }

// ---- cast x -> fp16 (padded rows zeroed) ----
__global__ __launch_bounds__(256) void castx_kernel(const float* __restrict__ x,
                                                    h16* __restrict__ xh,
                                                    long total, long valid) {
    long i = ((long)blockIdx.x * 256 + threadIdx.x) * 4;
    if (i >= total) return;
    float4 v = make_float4(0.f, 0.f, 0.f, 0.f);
    if (i < valid) v = *(const float4*)&x[i];
    half4v o; o.x = (h16)v.x; o.y = (h16)v.y; o.z = (h16)v.z; o.w = (h16)v.w;
    *(half4v*)&xh[i] = o;
}

// ---- weight prep: transpose+cast W1/W2, and append pre-contracted alpha cols ----
// w1t: [272][128] fp16  rows 0..255 = W1^T; 256..259 = W1@a_src1(h); 260..263 = W1@a_dst1(h); 264..271 zero
// w2t: [80][256]  fp16  rows 0..63  = W2^T; 64 = W2@a_src2; 65 = W2@a_dst2; 66..79 zero
__global__ __launch_bounds__(256) void prep_weights(const float* __restrict__ W1,
                                                    const float* __restrict__ W2,
                                                    const float* __restrict__ a_src1,
                                                    const float* __restrict__ a_dst1,
                                                    const float* __restrict__ a_src2,
                                                    const float* __restrict__ a_dst2,
                                                    h16* __restrict__ w1t,
                                                    h16* __restrict__ w2t) {
    const int t = threadIdx.x;
    if (blockIdx.x == 0) {
        // W1^T: col t of W1 -> row t of w1t
        for (int k = 0; k < IN_CH; ++k) w1t[t * IN_CH + k] = (h16)W1[k * D1 + t];
    } else if (blockIdx.x == 1) {
        if (t < HID)
            for (int k = 0; k < D1; ++k) w2t[t * D1 + k] = (h16)W2[k * HID + t];
        for (int i = t; i < 14 * D1; i += 256) w2t[66 * D1 + i] = (h16)0.f;
    } else if (blockIdx.x == 2) {
        // u1 vectors: 8 vecs x 128 entries
        for (int o = t; o < 1024; o += 256) {
            int v = o >> 7, k = o & 127;
            int h = v & 3;
            const float* avec = (v >> 2) ? (a_dst1 + h * HID) : (a_src1 + h * HID);
            const float* wrow = W1 + k * D1 + h * HID;
            float s = 0.f;
            for (int c = 0; c < HID; ++c) s += wrow[c] * avec[c];
            w1t[(256 + v) * IN_CH + k] = (h16)s;
            w1t[(264 + v) * IN_CH + k] = (h16)0.f;
        }
    } else {
        // u2 vectors: 2 vecs x 256 entries
        for (int o = t; o < 512; o += 256) {
            int v = o >> 8, k = o & 255;
            const float* avec = v ? a_dst2 : a_src2;
            const float* wrow = W2 + k * HID;
            float s = 0.f;
            for (int c = 0; c < HID; ++c) s += wrow[c] * avec[c];
            w2t[(64 + v) * D1 + k] = (h16)s;
        }
    }
}

// ---- MFMA GEMM1: h1[N,256](fp16) + asad[N,8] = xh[N,128] @ w1t ----
__global__ __launch_bounds__(256) void gemm1_mfma(const h16* __restrict__ xh,
                                                  const h16* __restrict__ w1t,
                                                  h16* __restrict__ h1,
                                                  float* __restrict__ asad, int n) {
    const int wave = threadIdx.x >> 6, lane = threadIdx.x & 63;
    const int r = lane & 15, ksel = lane >> 4;
    const int rowBase = blockIdx.x * 64 + wave * 16;
    const h16* xrow = xh + (size_t)(rowBase + r) * IN_CH + ksel * 8;
    half8v a[4];
    #pragma unroll
    for (int kk = 0; kk < 4; ++kk) a[kk] = *(const half8v*)(xrow + kk * 32);
    f32x4 acc[17];
    #pragma unroll
    for (int ct = 0; ct < 17; ++ct) acc[ct] = (f32x4){0.f, 0.f, 0.f, 0.f};
    #pragma unroll
    for (int ct = 0; ct < 17; ++ct) {
        const h16* wrow = w1t + (size_t)(ct * 16 + r) * IN_CH + ksel * 8;
        #pragma unroll
        for (int kk = 0; kk < 4; ++kk) {
            half8v b = *(const half8v*)(wrow + kk * 32);
            acc[ct] = __builtin_amdgcn_mfma_f32_16x16x32_f16(a[kk], b, acc[ct], 0, 0, 0);
        }
    }
    #pragma unroll
    for (int i = 0; i < 4; ++i) {
        int row = rowBase + ksel * 4 + i;
        if (row < n) {
            #pragma unroll
            for (int ct = 0; ct < 16; ++ct)
                h1[(size_t)row * D1 + ct * 16 + r] = (h16)acc[ct][i];
            if (r < 8) asad[(size_t)row * 8 + r] = acc[16][i];
        }
    }
}

// ---- MFMA GEMM2: h2[N,64](fp16) + asad2[N,2] = hmid[N,256] @ w2t ----
__global__ __launch_bounds__(256) void gemm2_mfma(const h16* __restrict__ hm,
                                                  const h16* __restrict__ w2t,
                                                  h16* __restrict__ h2,
                                                  float* __restrict__ asad2, int n) {
    const int wave = threadIdx.x >> 6, lane = threadIdx.x & 63;
    const int r = lane & 15, ksel = lane >> 4;
    const int rowBase = blockIdx.x * 64 + wave * 16;
    const h16* xrow = hm + (size_t)(rowBase + r) * D1 + ksel * 8;
    half8v a[8];
    #pragma unroll
    for (int kk = 0; kk < 8; ++kk) a[kk] = *(const half8v*)(xrow + kk * 32);
    f32x4 acc[5];
    #pragma unroll
    for (int ct = 0; ct < 5; ++ct) acc[ct] = (f32x4){0.f, 0.f, 0.f, 0.f};
    #pragma unroll
    for (int ct = 0; ct < 5; ++ct) {
        const h16* wrow = w2t + (size_t)(ct * 16 + r) * D1 + ksel * 8;
        #pragma unroll
        for (int kk = 0; kk < 8; ++kk) {
            half8v b = *(const half8v*)(wrow + kk * 32);
            acc[ct] = __builtin_amdgcn_mfma_f32_16x16x32_f16(a[kk], b, acc[ct], 0, 0, 0);
        }
    }
    #pragma unroll
    for (int i = 0; i < 4; ++i) {
        int row = rowBase + ksel * 4 + i;
        if (row < n) {
            #pragma unroll
            for (int ct = 0; ct < 4; ++ct)
                h2[(size_t)row * HID + ct * 16 + r] = (h16)acc[ct][i];
            if (r < 2) asad2[(size_t)row * 2 + r] = acc[4][i];
        }
    }
}

// ================= CSR build (by destination) =================
__global__ __launch_bounds__(256) void zero_kernel(int* __restrict__ cnt, int n) {
    int i = blockIdx.x * 256 + threadIdx.x;
    if (i < n) cnt[i] = 0;
}

__global__ __launch_bounds__(256) void hist_kernel(const int* __restrict__ ei,
                                                   int* __restrict__ cnt, int nE) {
    int e = blockIdx.x * 256 + threadIdx.x;
    if (e >= nE) return;
    atomicAdd(&cnt[ei[nE + e]], 1);
}

__global__ __launch_bounds__(256) void scan1_kernel(const int* __restrict__ cnt,
                                                    int* __restrict__ pre,
                                                    int* __restrict__ blockSums, int n) {
    __shared__ int lds[256];
    const int t = threadIdx.x;
    const int base = blockIdx.x * SCAN_BLK + t * 4;
    int v0 = 0, v1 = 0, v2 = 0, v3 = 0;
    if (base + 0 < n) v0 = cnt[base + 0];
    if (base + 1 < n) v1 = cnt[base + 1];
    if (base + 2 < n) v2 = cnt[base + 2];
    if (base + 3 < n) v3 = cnt[base + 3];
    int s = v0 + v1 + v2 + v3;
    lds[t] = s;
    __syncthreads();
    for (int off = 1; off < 256; off <<= 1) {
        int x = 0;
        if (t >= off) x = lds[t - off];
        __syncthreads();
        if (t >= off) lds[t] += x;
        __syncthreads();
    }
    int excl = lds[t] - s;
    if (t == 255) blockSums[blockIdx.x] = lds[255];
    if (base + 0 < n) pre[base + 0] = excl;
    if (base + 1 < n) pre[base + 1] = excl + v0;
    if (base + 2 < n) pre[base + 2] = excl + v0 + v1;
    if (base + 3 < n) pre[base + 3] = excl + v0 + v1 + v2;
}

__global__ void scan2_kernel(int* __restrict__ blockSums, int nb) {
    if (threadIdx.x == 0 && blockIdx.x == 0) {
        int acc = 0;
        for (int i = 0; i < nb; ++i) { int v = blockSums[i]; blockSums[i] = acc; acc += v; }
    }
}

__global__ __launch_bounds__(256) void scan3_kernel(int* __restrict__ pre,
                                                    const int* __restrict__ blockSums,
                                                    int* __restrict__ cursor, int n, int nE) {
    int i = blockIdx.x * 256 + threadIdx.x;
    if (i < n) {
        int v = pre[i] + blockSums[i / SCAN_BLK];
        pre[i] = v;
        cursor[i] = v;
    }
    if (i == 0) pre[n] = nE;
}

__global__ __launch_bounds__(256) void scatter_kernel(const int* __restrict__ ei,
                                                      int* __restrict__ cursor,
                                                      int* __restrict__ srcIdx,
                                                      int* __restrict__ dstIdx, int nE) {
    int e = blockIdx.x * 256 + threadIdx.x;
    if (e >= nE) return;
    int src = ei[e];
    int dst = ei[nE + e];
    int pos = atomicAdd(&cursor[dst], 1);
    srcIdx[pos] = src;
    dstIdx[pos] = dst;
}

// ---- edge weights, CSR order ----
__global__ __launch_bounds__(256) void ewt1_kernel(const int* __restrict__ srcIdx,
                                                   const int* __restrict__ dstIdx,
                                                   const float* __restrict__ asad,
                                                   float* __restrict__ wE1, int nE4) {
    int t = blockIdx.x * 256 + threadIdx.x;
    if (t >= nE4) return;
    int j = t >> 2, h = t & 3;
    int s = srcIdx[j], d = dstIdx[j];
    wE1[t] = expf(lrelu02(asad[(size_t)s * 8 + h] + asad[(size_t)d * 8 + 4 + h]));
}

__global__ __launch_bounds__(256) void ewt2_kernel(const int* __restrict__ srcIdx,
                                                   const int* __restrict__ dstIdx,
                                                   const float* __restrict__ asad2,
                                                   float* __restrict__ wE2, int nE) {
    int j = blockIdx.x * 256 + threadIdx.x;
    if (j >= nE) return;
    int s = srcIdx[j], d = dstIdx[j];
    wE2[j] = expf(lrelu02(asad2[(size_t)s * 2] + asad2[(size_t)d * 2 + 1]));
}

// ---- gather1: wave per dst node; precomputed weights; fused bias+LN+LeakyReLU ----
__global__ __launch_bounds__(256) void gather1_kernel(const h16* __restrict__ h1,
                                                      const float* __restrict__ asad,
                                                      const float* __restrict__ wE1,
                                                      const int* __restrict__ rowStart,
                                                      const int* __restrict__ srcIdx,
                                                      const float* __restrict__ b1,
                                                      const float* __restrict__ gamma,
                                                      const float* __restrict__ beta,
                                                      h16* __restrict__ hmid, int n, int npad) {
    const int lane = threadIdx.x & 63;
    const int node = (blockIdx.x * 256 + threadIdx.x) >> 6;
    if (node >= npad) return;
    if (node >= n) {            // zero pad rows (gemm2 reads them)
        half4v z = {(h16)0.f, (h16)0.f, (h16)0.f, (h16)0.f};
        *(half4v*)&hmid[(size_t)node * D1 + lane * 4] = z;
        return;
    }
    const int hh = lane >> 4;
    const float w = expf(lrelu02(asad[(size_t)node * 8 + hh] +
                                 asad[(size_t)node * 8 + 4 + hh]));  // self-loop
    half4v sv = *(const half4v*)&h1[(size_t)node * D1 + lane * 4];
    float4 acc = make_float4((float)sv.x * w, (float)sv.y * w,
                             (float)sv.z * w, (float)sv.w * w);
    float den = w;
    const int beg = rowStart[node], end = rowStart[node + 1];
    int j = beg;
    for (; j + 3 < end; j += 4) {
        int s0 = srcIdx[j + 0];
        int s1 = srcIdx[j + 1];
        int s2 = srcIdx[j + 2];
        int s3 = srcIdx[j + 3];
        float w0 = wE1[(size_t)(j + 0) * 4 + hh];
        float w1 = wE1[(size_t)(j + 1) * 4 + hh];
        float w2 = wE1[(size_t)(j + 2) * 4 + hh];
        float w3 = wE1[(size_t)(j + 3) * 4 + hh];
        half4v r0 = *(const half4v*)&h1[(size_t)s0 * D1 + lane * 4];
        half4v r1 = *(const half4v*)&h1[(size_t)s1 * D1 + lane * 4];
        half4v r2 = *(const half4v*)&h1[(size_t)s2 * D1 + lane * 4];
        half4v r3 = *(const half4v*)&h1[(size_t)s3 * D1 + lane * 4];
        acc.x = fmaf((float)r0.x, w0, acc.x); acc.y = fmaf((float)r0.y, w0, acc.y);
        acc.z = fmaf((float)r0.z, w0, acc.z); acc.w = fmaf((float)r0.w, w0, acc.w);
        acc.x = fmaf((float)r1.x, w1, acc.x); acc.y = fmaf((float)r1.y, w1, acc.y);
        acc.z = fmaf((float)r1.z, w1, acc.z); acc.w = fmaf((float)r1.w, w1, acc.w);
        acc.x = fmaf((float)r2.x, w2, acc.x); acc.y = fmaf((float)r2.y, w2, acc.y);
        acc.z = fmaf((float)r2.z, w2, acc.z); acc.w = fmaf((float)r2.w, w2, acc.w);
        acc.x = fmaf((float)r3.x, w3, acc.x); acc.y = fmaf((float)r3.y, w3, acc.y);
        acc.z = fmaf((float)r3.z, w3, acc.z); acc.w = fmaf((float)r3.w, w3, acc.w);
        den += w0 + w1 + w2 + w3;
    }
    for (; j < end; ++j) {
        int s = srcIdx[j];
        float wj = wE1[(size_t)j * 4 + hh];
        half4v xv = *(const half4v*)&h1[(size_t)s * D1 + lane * 4];
        acc.x = fmaf((float)xv.x, wj, acc.x);
        acc.y = fmaf((float)xv.y, wj, acc.y);
        acc.z = fmaf((float)xv.z, wj, acc.z);
        acc.w = fmaf((float)xv.w, wj, acc.w);
        den += wj;
    }
    float inv = 1.f / (den + 1e-16f);
    float4 bv = *(const float4*)&b1[lane * 4];
    float4 y;
    y.x = acc.x * inv + bv.x; y.y = acc.y * inv + bv.y;
    y.z = acc.z * inv + bv.z; y.w = acc.w * inv + bv.w;
    float s = y.x + y.y + y.z + y.w;
    #pragma unroll
    for (int off = 1; off < 64; off <<= 1) s += __shfl_xor(s, off, 64);
    float mu = s * (1.f / 256.f);
    float4 dx;
    dx.x = y.x - mu; dx.y = y.y - mu; dx.z = y.z - mu; dx.w = y.w - mu;
    float sq = dx.x * dx.x + dx.y * dx.y + dx.z * dx.z + dx.w * dx.w;
    #pragma unroll
    for (int off = 1; off < 64; off <<= 1) sq += __shfl_xor(sq, off, 64);
    float rs = rsqrtf(sq * (1.f / 256.f) + 1e-5f);
    float4 g = *(const float4*)&gamma[lane * 4];
    float4 be = *(const float4*)&beta[lane * 4];
    half4v o;
    o.x = (h16)lrelu001(dx.x * rs * g.x + be.x);
    o.y = (h16)lrelu001(dx.y * rs * g.y + be.y);
    o.z = (h16)lrelu001(dx.z * rs * g.z + be.z);
    o.w = (h16)lrelu001(dx.w * rs * g.w + be.w);
    *(half4v*)&hmid[(size_t)node * D1 + lane * 4] = o;
}

// ---- gather2: wave per dst node (1 head x 64 ch); precomputed weights ----
__global__ __launch_bounds__(256) void gather2_kernel(const h16* __restrict__ h2,
                                                      const float* __restrict__ asad2,
                                                      const float* __restrict__ wE2,
                                                      const int* __restrict__ rowStart,
                                                      const int* __restrict__ srcIdx,
                                                      const float* __restrict__ b2,
                                                      float* __restrict__ out, int n) {
    const int lane = threadIdx.x & 63;
    const int node = (blockIdx.x * 256 + threadIdx.x) >> 6;
    if (node >= n) return;
    const float w = expf(lrelu02(asad2[(size_t)node * 2] + asad2[(size_t)node * 2 + 1]));
    float acc = (float)h2[(size_t)node * HID + lane] * w;
    float den = w;
    const int beg = rowStart[node], end = rowStart[node + 1];
    int j = beg;
    for (; j + 7 < end; j += 8) {
        float wv[8]; float vv[8];
        #pragma unroll
        for (int q = 0; q < 8; ++q) {
            int s = srcIdx[j + q];
            wv[q] = wE2[j + q];
            vv[q] = (float)h2[(size_t)s * HID + lane];
        }
        #pragma unroll
        for (int q = 0; q < 8; ++q) { acc = fmaf(vv[q], wv[q], acc); den += wv[q]; }
    }
    for (; j < end; ++j) {
        int s = srcIdx[j];
        float wj = wE2[j];
        acc = fmaf((float)h2[(size_t)s * HID + lane], wj, acc);
        den += wj;
    }
    out[(size_t)node * HID + lane] = acc / (den + 1e-16f) + b2[lane];
}

extern "C" void kernel_launch(void* const* d_in, const int* in_sizes, int n_in,
                              void* d_out, int out_size, void* d_ws, size_t ws_size,
                              hipStream_t stream) {
    const float* x      = (const float*)d_in[0];
    const int*   ei     = (const int*)d_in[1];
    const float* W1     = (const float*)d_in[2];
    const float* a_src1 = (const float*)d_in[3];
    const float* a_dst1 = (const float*)d_in[4];
    const float* b1     = (const float*)d_in[5];
    const float* gamma  = (const float*)d_in[6];
    const float* beta   = (const float*)d_in[7];
    const float* W2     = (const float*)d_in[8];
    const float* a_src2 = (const float*)d_in[9];
    const float* a_dst2 = (const float*)d_in[10];
    const float* b2     = (const float*)d_in[11];
    float* out = (float*)d_out;

    const int N = in_sizes[0] / IN_CH;
    const int E = in_sizes[1] / 2;
    const int NP = (N + 63) & ~63;          // row-pad for 64-row MFMA tiles

    // workspace layout (float slots)
    float* ws = (float*)d_ws;
    size_t off = 0;
    h16*   h1   = (h16*)(ws + off); off += (size_t)128 * N;    // N*256 halfs
    h16*   xh   = (h16*)(ws + off); off += (size_t)64 * NP;    // NP*128 halfs
    h16*   hmid = (h16*)(ws + off); off += (size_t)128 * NP;   // NP*256 halfs
    h16*   h2   = (h16*)(ws + off); off += (size_t)32 * N;     // N*64 halfs
    h16*   w1t  = (h16*)(ws + off); off += 272 * IN_CH / 2;    // 272x128 halfs
    h16*   w2t  = (h16*)(ws + off); off += 80 * D1 / 2;        // 80x256 halfs
    float* asad = ws + off;         off += (size_t)8 * N;      // [N][8] (src 0..3, dst 4..7)
    float* asad2= ws + off;         off += (size_t)2 * N;      // [N][2]
    float* wE1  = ws + off;         off += (size_t)4 * E;      // CSR-order weights, 4 heads
    float* wE2  = ws + off;         off += (size_t)E;
    int* srcIdx    = (int*)(ws + off); off += E;
    int* dstIdx    = (int*)(ws + off); off += E;
    int* rowStart  = (int*)(ws + off); off += N + 1;
    int* cursor    = (int*)(ws + off); off += N;
    int* blockSums = (int*)(ws + off);

    const int nodeBlocks  = (N + 3) / 4;
    const int nodeBlocksP = (NP + 3) / 4;
    const int nThreadBlocksN = (N + 255) / 256;
    const int nThreadBlocksE = (E + 255) / 256;
    const int scanBlocks = (N + SCAN_BLK - 1) / SCAN_BLK;

    // prep
    castx_kernel<<<(NP * IN_CH / 4 + 255) / 256, 256, 0, stream>>>(
        x, xh, (long)NP * IN_CH, (long)N * IN_CH);
    prep_weights<<<4, 256, 0, stream>>>(W1, W2, a_src1, a_dst1, a_src2, a_dst2, w1t, w2t);

    // CSR build (by destination)
    zero_kernel<<<nThreadBlocksN, 256, 0, stream>>>(cursor, N);
    hist_kernel<<<nThreadBlocksE, 256, 0, stream>>>(ei, cursor, E);
    scan1_kernel<<<scanBlocks, 256, 0, stream>>>(cursor, rowStart, blockSums, N);
    scan2_kernel<<<1, 64, 0, stream>>>(blockSums, scanBlocks);
    scan3_kernel<<<nThreadBlocksN, 256, 0, stream>>>(rowStart, blockSums, cursor, N, E);
    scatter_kernel<<<nThreadBlocksE, 256, 0, stream>>>(ei, cursor, srcIdx, dstIdx, E);

    // layer 1
    gemm1_mfma<<<NP / 64, 256, 0, stream>>>(xh, w1t, h1, asad, N);
    ewt1_kernel<<<(4 * E + 255) / 256, 256, 0, stream>>>(srcIdx, dstIdx, asad, wE1, 4 * E);
    gather1_kernel<<<nodeBlocksP, 256, 0, stream>>>(h1, asad, wE1, rowStart, srcIdx,
                                                    b1, gamma, beta, hmid, N, NP);
    // layer 2
    gemm2_mfma<<<NP / 64, 256, 0, stream>>>(hmid, w2t, h2, asad2, N);
    ewt2_kernel<<<nThreadBlocksE, 256, 0, stream>>>(srcIdx, dstIdx, asad2, wE2, E);
    gather2_kernel<<<nodeBlocks, 256, 0, stream>>>(h2, asad2, wE2, rowStart, srcIdx,
                                                   b2, out, N);
}